// Round 10
// baseline (61.448 us; speedup 1.0000x reference)
//
#include <hip/hip_runtime.h>
#include <float.h>

// EuclideanCodebook R10: R9 + register-PIN of x fragments.
// R9 postmortem: VGPR_Count=100 (nominal 160+) => compiler rematerialized the
// 32 f16x8 x-fragments (reload+re-convert) EVERY chunk -> VALUBusy 29%.
// Fix: empty inline-asm "+v" anchors make each fragment's producer opaque ->
// compiler must keep them resident (128 VGPRs) across the chunk loop.
// Everything else identical to R9 (16x16x32 f16-split, 8 indep acc chains,
// wave-linear fragment image, CH=64 DMA dbuf, vmcnt(8), 2 blocks/CU).

#define Cdim        128
#define KCODES      1024
#define CH          64
#define NCH         16
#define BROWS       128       // 2 row-groups x 64 rows; wave pair splits codes
#define THREADS     256
#define IMG_OFF     4096
#define CHUNK_BYTES 32768     // [hi: (ctg*4+ks)*1KB x16 | lo: +16KB]

typedef _Float16 f16;
typedef __attribute__((ext_vector_type(8))) _Float16 f16x8;
typedef __attribute__((ext_vector_type(4))) float    f32x4;

#define MFMA16(A, B, C) __builtin_amdgcn_mfma_f32_16x16x32_f16((A), (B), (C), 0, 0, 0)

// liveness anchor: forces v into VGPRs here and makes its producer opaque
// (prevents rematerialization of the conversion chain inside the K-loop).
#define PIN(v) asm volatile("" : "+v"(v))

// ---------------- e_sq pre-pass (exact fp32) ----------------
__global__ __launch_bounds__(256) void esq_kernel(const float* __restrict__ embed,
                                                  float* __restrict__ esq, int K) {
    int gid  = blockIdx.x * blockDim.x + threadIdx.x;
    int code = gid >> 6;
    int lane = threadIdx.x & 63;
    if (code >= K) return;
    float2 v = ((const float2*)(embed + (size_t)code * Cdim))[lane];
    float  s = fmaf(v.x, v.x, v.y * v.y);
    #pragma unroll
    for (int m = 32; m >= 1; m >>= 1) s += __shfl_xor(s, m, 64);
    if (lane == 0) esq[code] = s;
}

__device__ __forceinline__ void cvt8s(float4 a, float4 b, float scale,
                                      f16x8& h, f16x8& lo) {
    float v[8] = {a.x, a.y, a.z, a.w, b.x, b.y, b.z, b.w};
    #pragma unroll
    for (int i = 0; i < 8; ++i) {
        float s = v[i] * scale;
        f16 hh = (f16)s;
        h[i]  = hh;
        lo[i] = (f16)(s - (float)hh);
    }
}

// ---- codebook -> 16x16x32-fragment image, wave-linear lane order ----
// A-frag: lane l holds e[code = base + (l&15)][k = ks*32+(l>>4)*8 ..+8]
// hi addr: IMG_OFF + ch*32768 + (ctg*4+ks)*1024 + ((l>>4)*16 + (l&15))*16; lo +16384
__global__ __launch_bounds__(256) void bconv_kernel(const float* __restrict__ embed,
                                                    char* __restrict__ ws) {
    int t    = blockIdx.x * 256 + threadIdx.x;   // 16384 threads
    int code = t >> 4;
    int seg  = t & 15;
    int ks   = seg >> 2;
    int kseg = seg & 3;
    int ch = code >> 6, ctg = (code >> 4) & 3, lr = code & 15;
    const float4* p = (const float4*)(embed + (size_t)code * Cdim + ks * 32 + kseg * 8);
    f16x8 h, lo;
    cvt8s(p[0], p[1], 1.0f, h, lo);
    size_t base = (size_t)IMG_OFF + (size_t)ch * CHUNK_BYTES
                + (ctg * 4 + ks) * 1024 + (kseg * 16 + lr) * 16;
    *(f16x8*)(ws + base)         = h;
    *(f16x8*)(ws + base + 16384) = lo;
}

// ---------------- async global->LDS 16B ----------------
__device__ __forceinline__ void gll16(const void* g, void* l) {
    __builtin_amdgcn_global_load_lds(
        (const __attribute__((address_space(1))) unsigned int*)g,
        (__attribute__((address_space(3))) unsigned int*)l, 16, 0, 0);
}

__global__ __launch_bounds__(THREADS, 2) void vq_kernel(
    const float* __restrict__ x, const float* __restrict__ embed,
    const char* __restrict__ ws, float* __restrict__ outq,
    float* __restrict__ outi) {

    __shared__ __align__(16) char  Bb[2][CHUNK_BYTES];   // 64KB dbuf
    __shared__ __align__(16) float esq_lds[KCODES];      // 4KB
    __shared__ float mrg_v[2][BROWS];
    __shared__ int   mrg_i[2][BROWS];
    __shared__ int   winners[BROWS];

    const int tid  = threadIdx.x;
    const int wid  = tid >> 6;          // wave 0..3
    const int l    = tid & 63;
    const int lr   = l & 15;            // x-row within 16-tile / code within frag
    const int lg   = l >> 4;            // k-seg (inputs) / code-subrow (outputs)
    const int wr   = wid & 1;           // row group (64 rows)
    const int nt   = wid >> 1;          // code half of each chunk
    const int row0 = blockIdx.x * BROWS;

    // ---- prologue DMA: chunk 0 (8KB/wave) + esq (1KB/wave) ----
    {
        const char* src = ws + IMG_OFF + wid * 8192 + (size_t)l * 16;
        char*       dst = &Bb[0][wid * 8192];
        #pragma unroll
        for (int i = 0; i < 8; ++i) gll16(src + i * 1024, dst + i * 1024);
        gll16(ws + wid * 1024 + (size_t)l * 16, (char*)esq_lds + wid * 1024);
    }

    // ---- x rows -> B-fragments (2*xh, 2*xl), then PIN in registers ----
    f16x8 bxh[4][4], bxl[4][4];
    #pragma unroll
    for (int rt = 0; rt < 4; ++rt) {
        const float* xr = x + (size_t)(row0 + wr * 64 + rt * 16 + lr) * Cdim + lg * 8;
        #pragma unroll
        for (int ks = 0; ks < 4; ++ks) {
            float4 v0 = *(const float4*)(xr + ks * 32);
            float4 v1 = *(const float4*)(xr + ks * 32 + 4);
            cvt8s(v0, v1, 2.0f, bxh[rt][ks], bxl[rt][ks]);
            PIN(bxh[rt][ks]);
            PIN(bxl[rt][ks]);
        }
    }

    float best[4];
    int   bidx[4];
    #pragma unroll
    for (int rt = 0; rt < 4; ++rt) { best[rt] = -FLT_MAX; bidx[rt] = 0; }

    #pragma unroll 1
    for (int ch = 0; ch < NCH; ++ch) {
        const int cur = ch & 1, nxt = cur ^ 1;

        __builtin_amdgcn_s_barrier();            // all done reading Bb[nxt]
        if (ch + 1 < NCH) {
            const char* src = ws + IMG_OFF + (size_t)(ch + 1) * CHUNK_BYTES
                            + wid * 8192 + (size_t)l * 16;
            char* dst = &Bb[nxt][wid * 8192];
            #pragma unroll
            for (int i = 0; i < 8; ++i) gll16(src + i * 1024, dst + i * 1024);
            asm volatile("s_waitcnt vmcnt(8)" ::: "memory");   // chunk ch staged
        } else {
            asm volatile("s_waitcnt vmcnt(0)" ::: "memory");
        }
        __builtin_amdgcn_s_barrier();            // chunk ch visible block-wide

        // 8 independent accumulator chains: acc[ct][rt]
        f32x4 acc[2][4];
        #pragma unroll
        for (int ct = 0; ct < 2; ++ct)
            #pragma unroll
            for (int rt = 0; rt < 4; ++rt)
                acc[ct][rt] = (f32x4){0.f, 0.f, 0.f, 0.f};

        const char* bb = &Bb[cur][(size_t)l * 16];

        #pragma unroll
        for (int ks = 0; ks < 4; ++ks) {
            // A-frags (codebook): identity lane pattern, conflict-free
            f16x8 eh0 = *(const f16x8*)(bb + ((nt * 2 + 0) * 4 + ks) * 1024);
            f16x8 el0 = *(const f16x8*)(bb + ((nt * 2 + 0) * 4 + ks) * 1024 + 16384);
            f16x8 eh1 = *(const f16x8*)(bb + ((nt * 2 + 1) * 4 + ks) * 1024);
            f16x8 el1 = *(const f16x8*)(bb + ((nt * 2 + 1) * 4 + ks) * 1024 + 16384);

            __builtin_amdgcn_s_setprio(1);
            // pass 1: eh * 2xh   (same-acc reuse distance = 8 MFMAs)
            #pragma unroll
            for (int rt = 0; rt < 4; ++rt) acc[0][rt] = MFMA16(eh0, bxh[rt][ks], acc[0][rt]);
            #pragma unroll
            for (int rt = 0; rt < 4; ++rt) acc[1][rt] = MFMA16(eh1, bxh[rt][ks], acc[1][rt]);
            // pass 2: eh * 2xl
            #pragma unroll
            for (int rt = 0; rt < 4; ++rt) acc[0][rt] = MFMA16(eh0, bxl[rt][ks], acc[0][rt]);
            #pragma unroll
            for (int rt = 0; rt < 4; ++rt) acc[1][rt] = MFMA16(eh1, bxl[rt][ks], acc[1][rt]);
            // pass 3: el * 2xh
            #pragma unroll
            for (int rt = 0; rt < 4; ++rt) acc[0][rt] = MFMA16(el0, bxh[rt][ks], acc[0][rt]);
            #pragma unroll
            for (int rt = 0; rt < 4; ++rt) acc[1][rt] = MFMA16(el1, bxh[rt][ks], acc[1][rt]);
            __builtin_amdgcn_s_setprio(0);
        }

        // scoring: s = 2*dot - e^2; lane's codes = cb + lg*4 + j (ascending)
        #pragma unroll
        for (int ct = 0; ct < 2; ++ct) {
            const int cb = ch * CH + (nt * 2 + ct) * 16 + lg * 4;
            float4 e4 = *(const float4*)&esq_lds[cb];
            #pragma unroll
            for (int rt = 0; rt < 4; ++rt) {
                #pragma unroll
                for (int j = 0; j < 4; ++j) {
                    float s = acc[ct][rt][j] - ((const float*)&e4)[j];
                    if (s > best[rt]) { best[rt] = s; bidx[rt] = cb + j; }
                }
            }
        }
    }

    // ---- reduce over lg (lanes lr, lr+16, lr+32, lr+48 share each row) ----
    #pragma unroll
    for (int rt = 0; rt < 4; ++rt) {
        float bs = best[rt]; int bi = bidx[rt];
        #pragma unroll
        for (int m = 16; m <= 32; m <<= 1) {
            float vs = __shfl_xor(bs, m, 64);
            int   vi = __shfl_xor(bi, m, 64);
            if (vs > bs || (vs == bs && vi < bi)) { bs = vs; bi = vi; }
        }
        if (lg == 0) {
            mrg_v[nt][wr * 64 + rt * 16 + lr] = bs;
            mrg_i[nt][wr * 64 + rt * 16 + lr] = bi;
        }
    }
    __syncthreads();
    if (tid < BROWS) {
        float v0 = mrg_v[0][tid]; int i0 = mrg_i[0][tid];
        float v1 = mrg_v[1][tid]; int i1 = mrg_i[1][tid];
        int bi = (v1 > v0 || (v1 == v0 && i1 < i0)) ? i1 : i0;
        winners[tid] = bi;
        outi[row0 + tid] = (float)bi;
    }
    __syncthreads();

    // ---- gather quantized = embed[winner] (exact fp32 copy) ----
    #pragma unroll
    for (int i = 0; i < 16; ++i) {
        int pos = i * THREADS + tid;
        int r = pos >> 5, c4 = pos & 31;
        int idx = winners[r];
        float4 v = ((const float4*)(embed + (size_t)idx * Cdim))[c4];
        ((float4*)(outq + (size_t)(row0 + r) * Cdim))[c4] = v;
    }
}

extern "C" void kernel_launch(void* const* d_in, const int* in_sizes, int n_in,
                              void* d_out, int out_size, void* d_ws, size_t ws_size,
                              hipStream_t stream) {
    const float* x     = (const float*)d_in[0];
    const float* embed = (const float*)d_in[1];
    const int M = in_sizes[0] / Cdim;   // 65536
    const int K = in_sizes[1] / Cdim;   // 1024
    float* outq = (float*)d_out;
    float* outi = outq + (size_t)M * Cdim;

    esq_kernel <<<K / 4, 256, 0, stream>>>(embed, (float*)d_ws, K);
    bconv_kernel<<<64, 256, 0, stream>>>(embed, (char*)d_ws);
    vq_kernel  <<<M / BROWS, THREADS, 0, stream>>>(x, embed, (const char*)d_ws,
                                                   outq, outi);
}